// Round 2
// baseline (2096.031 us; speedup 1.0000x reference)
//
#include <hip/hip_runtime.h>
#include <stdint.h>

typedef _Float16 h8 __attribute__((ext_vector_type(8)));
typedef float f4 __attribute__((ext_vector_type(4)));

#define DEV __device__ __forceinline__

DEV float lrelu(float v){ return v >= 0.f ? v : 0.1f * v; }

DEV void gl_lds16(const void* g, void* l){
  __builtin_amdgcn_global_load_lds(
      (const __attribute__((address_space(1))) void*)g,
      (__attribute__((address_space(3))) void*)l, 16, 0, 0);
}

// ---------------------------------------------------------------------------
// GEMM: acc[m][n] = sum_k A[m][k] * B[n][k]   (A: [M][K] f16, B: [N][K] f16)
// MODE 0: D[((m&63)*256 + (m>>6))*N + n] = acc + bias[n]          (U-path -> c[t][b][n])
// MODE 1: D[m*N+n] = lrelu(acc + bias[n] + Cterm[m*N+n])          (scan step)
// MODE 2: D[m*N+n] = lrelu(acc + bias[n])                         (MLP layers)
// ---------------------------------------------------------------------------
template<int BM,int BN,int BK,int WR,int WC,int MODE>
__global__ __launch_bounds__(WR*WC*64)
void gemm_bt(const _Float16* __restrict__ A, const _Float16* __restrict__ Bw,
             const float* __restrict__ bias, const _Float16* __restrict__ Cterm,
             _Float16* __restrict__ D, int M, int N, int K)
{
  constexpr int NW  = WR*WC;
  constexpr int WMT = BM/WR, WNT = BN/WC;
  constexpr int MI  = WMT/16, NI = WNT/16;
  constexpr int RPI = 512/BK;                 // rows per 1KB global_load_lds issue
  constexpr int AIS = BM/RPI/NW, BIS = BN/RPI/NW;
  static_assert(AIS*RPI*NW == BM && BIS*RPI*NW == BN, "tile/stage mismatch");

  __shared__ __align__(16) _Float16 As[BM][BK];
  __shared__ __align__(16) _Float16 Bs[BN][BK];

  int wg = blockIdx.x;
  { int q = (int)gridDim.x >> 3; wg = (wg & 7) * q + (wg >> 3); }  // XCD swizzle (grids %8==0)
  const int nt = N / BN;
  const int m0 = (wg / nt) * BM, n0 = (wg % nt) * BN;

  const int tid = threadIdx.x, w = tid >> 6, lane = tid & 63;
  const int wm = (w / WC) * WMT, wn = (w % WC) * WNT;
  const int lrow = lane / (BK/8), lkb = (lane % (BK/8)) * 8;
  const int fr = lane & 15, fk = (lane >> 4) * 8, rrow = (lane >> 4) * 4;

  f4 acc[MI][NI];
  f4 zero = {0.f, 0.f, 0.f, 0.f};
  #pragma unroll
  for (int i = 0; i < MI; ++i)
    #pragma unroll
    for (int j = 0; j < NI; ++j) acc[i][j] = zero;

  for (int k0 = 0; k0 < K; k0 += BK) {
    __syncthreads();
    #pragma unroll
    for (int i = 0; i < AIS; ++i) {
      const int r0 = (w*AIS + i) * RPI;
      gl_lds16(A + (size_t)(m0 + r0 + lrow)*K + (k0 + lkb), (void*)&As[r0][0]);
    }
    #pragma unroll
    for (int i = 0; i < BIS; ++i) {
      const int r0 = (w*BIS + i) * RPI;
      gl_lds16(Bw + (size_t)(n0 + r0 + lrow)*K + (k0 + lkb), (void*)&Bs[r0][0]);
    }
    __syncthreads();
    #pragma unroll
    for (int kk = 0; kk < BK; kk += 32) {
      h8 af[MI], bf[NI];
      #pragma unroll
      for (int mi = 0; mi < MI; ++mi) af[mi] = *(const h8*)&As[wm + mi*16 + fr][kk + fk];
      #pragma unroll
      for (int ni = 0; ni < NI; ++ni) bf[ni] = *(const h8*)&Bs[wn + ni*16 + fr][kk + fk];
      #pragma unroll
      for (int mi = 0; mi < MI; ++mi)
        #pragma unroll
        for (int ni = 0; ni < NI; ++ni)
          acc[mi][ni] = __builtin_amdgcn_mfma_f32_16x16x32_f16(af[mi], bf[ni], acc[mi][ni], 0, 0, 0);
    }
  }

  #pragma unroll
  for (int mi = 0; mi < MI; ++mi)
    #pragma unroll
    for (int ni = 0; ni < NI; ++ni) {
      const int n = n0 + wn + ni*16 + fr;
      const float bv = bias[n];
      #pragma unroll
      for (int r = 0; r < 4; ++r) {
        const int m = m0 + wm + mi*16 + rrow + r;
        float v = acc[mi][ni][r] + bv;
        if constexpr (MODE == 0) {
          D[(size_t)((m & 63)*256 + (m >> 6)) * N + n] = (_Float16)v;
        } else if constexpr (MODE == 1) {
          v += (float)Cterm[(size_t)m * N + n];
          v = lrelu(v);
          D[(size_t)m * N + n] = (_Float16)v;
        } else {
          v = lrelu(v);
          D[(size_t)m * N + n] = (_Float16)v;
        }
      }
    }
}

// ---------------------------------------------------------------------------
// Prep / elementwise kernels (all vectorized 8 elems/thread, grid-stride)
// ---------------------------------------------------------------------------
__global__ void k_f2h(const float* __restrict__ s, _Float16* __restrict__ d, long n8){
  const long str = (long)gridDim.x * blockDim.x;
  for (long i = (long)blockIdx.x*blockDim.x + threadIdx.x; i < n8; i += str){
    const long e = i*8;
    f4 a = *(const f4*)(s+e), b = *(const f4*)(s+e+4);
    h8 h = {(_Float16)a[0],(_Float16)a[1],(_Float16)a[2],(_Float16)a[3],
            (_Float16)b[0],(_Float16)b[1],(_Float16)b[2],(_Float16)b[3]};
    *(h8*)(d+e) = h;
  }
}

// W = [[Ar, -Ai],[Ai, Ar]] (1536x1536 f16), bias = [br-bi ; br+bi]
__global__ void k_build_cplx(const float* __restrict__ Ar, const float* __restrict__ Ai,
                             const float* __restrict__ br, const float* __restrict__ bi,
                             _Float16* __restrict__ W, float* __restrict__ bias)
{
  const long n8 = 1536L*1536/8;
  const long str = (long)gridDim.x*blockDim.x;
  const long t0 = (long)blockIdx.x*blockDim.x + threadIdx.x;
  if (t0 < 1536) bias[t0] = (t0 < 768) ? br[t0] - bi[t0] : br[t0-768] + bi[t0-768];
  for (long i = t0; i < n8; i += str){
    const long e = i*8;
    const int n = (int)(e / 1536), k = (int)(e % 1536);
    const float* src; float sg = 1.f;
    if (n < 768) { if (k < 768) src = Ar + (long)n*768 + k; else { src = Ai + (long)n*768 + (k-768); sg = -1.f; } }
    else         { if (k < 768) src = Ai + (long)(n-768)*768 + k; else src = Ar + (long)(n-768)*768 + (k-768); }
    f4 a = *(const f4*)src, b = *(const f4*)(src+4);
    h8 h = {(_Float16)(a[0]*sg),(_Float16)(a[1]*sg),(_Float16)(a[2]*sg),(_Float16)(a[3]*sg),
            (_Float16)(b[0]*sg),(_Float16)(b[1]*sg),(_Float16)(b[2]*sg),(_Float16)(b[3]*sg)};
    *(h8*)(W + e) = h;
  }
}

// W = [lr ; li]  ((2*Nh) x K f16)
__global__ void k_build_cat(const float* __restrict__ lr, const float* __restrict__ li,
                            _Float16* __restrict__ W, int Nh, int K)
{
  const long n8 = (long)Nh*2*K/8;
  const long str = (long)gridDim.x*blockDim.x;
  for (long i = (long)blockIdx.x*blockDim.x + threadIdx.x; i < n8; i += str){
    const long e = i*8;
    const int n = (int)(e / K), k = (int)(e % K);
    const float* src = (n < Nh) ? lr + (long)n*K + k : li + (long)(n-Nh)*K + k;
    f4 a = *(const f4*)src, b = *(const f4*)(src+4);
    h8 h = {(_Float16)a[0],(_Float16)a[1],(_Float16)a[2],(_Float16)a[3],
            (_Float16)b[0],(_Float16)b[1],(_Float16)b[2],(_Float16)b[3]};
    *(h8*)(W + e) = h;
  }
}

__global__ void k_cat_bias(const float* __restrict__ brr, const float* __restrict__ bii,
                           float* __restrict__ bias, int Nh){
  const int t = blockIdx.x*blockDim.x + threadIdx.x;
  if (t < 2*Nh) bias[t] = (t < Nh) ? brr[t] : bii[t - Nh];
}

// h0 f16 [256][1536] = [h0r | h0i]
__global__ void k_hinit(const float* __restrict__ h0r, const float* __restrict__ h0i,
                        _Float16* __restrict__ h){
  const long n8 = 256L*1536/8;
  const long str = (long)gridDim.x*blockDim.x;
  for (long i = (long)blockIdx.x*blockDim.x + threadIdx.x; i < n8; i += str){
    const long e = i*8;
    const int b = (int)(e / 1536), j = (int)(e % 1536);
    const float* src = (j < 768) ? h0r + (long)b*768 + j : h0i + (long)b*768 + (j-768);
    f4 a = *(const f4*)src, c = *(const f4*)(src+4);
    h8 h2 = {(_Float16)a[0],(_Float16)a[1],(_Float16)a[2],(_Float16)a[3],
             (_Float16)c[0],(_Float16)c[1],(_Float16)c[2],(_Float16)c[3]};
    *(h8*)(h + e) = h2;
  }
}

// A2 [512][768] = [hr ; hi] from h [256][1536]
__global__ void k_pack(const _Float16* __restrict__ h, _Float16* __restrict__ A2){
  const long n8 = 512L*768/8;
  const long str = (long)gridDim.x*blockDim.x;
  for (long i = (long)blockIdx.x*blockDim.x + threadIdx.x; i < n8; i += str){
    const long e = i*8;
    const int m = (int)(e / 768), k = (int)(e % 768);
    const _Float16* src = (m < 256) ? h + (long)m*1536 + k : h + (long)(m-256)*1536 + 768 + k;
    *(h8*)(A2 + e) = *(const h8*)src;
  }
}

// y[b][j] = LC[b][j] - LC[256+b][3072+j] ; y[256+b][j] = LC[256+b][j] + LC[b][3072+j]
__global__ void k_combine(const _Float16* __restrict__ LC, _Float16* __restrict__ y){
  const long n8 = 256L*3072/8;
  const long str = (long)gridDim.x*blockDim.x;
  for (long i = (long)blockIdx.x*blockDim.x + threadIdx.x; i < n8; i += str){
    const long e = i*8;
    const int b = (int)(e / 3072), j = (int)(e % 3072);
    h8 arr = *(const h8*)(LC + (long)b*6144 + j);
    h8 aii = *(const h8*)(LC + (long)(256+b)*6144 + 3072 + j);
    h8 air = *(const h8*)(LC + (long)(256+b)*6144 + j);
    h8 ari = *(const h8*)(LC + (long)b*6144 + 3072 + j);
    h8 yr, yi;
    #pragma unroll
    for (int t = 0; t < 8; ++t){
      yr[t] = (_Float16)((float)arr[t] - (float)aii[t]);
      yi[t] = (_Float16)((float)air[t] + (float)ari[t]);
    }
    *(h8*)(y + (long)b*3072 + j) = yr;
    *(h8*)(y + (long)(256+b)*3072 + j) = yi;
  }
}

// out[b] = lrelu( dot(concat(xrn[b], xin[b]), w5) + b5 )
__global__ void k_final(const _Float16* __restrict__ y, const float* __restrict__ w5,
                        const float* __restrict__ b5, float* __restrict__ out){
  const int b = blockIdx.x, tid = threadIdx.x;
  float s = 0.f;
  for (int j = tid; j < 6144; j += 256){
    float v = (j < 3072) ? (float)y[(long)b*3072 + j] : (float)y[(long)(256+b)*3072 + (j-3072)];
    s += v * w5[j];
  }
  #pragma unroll
  for (int off = 32; off; off >>= 1) s += __shfl_down(s, off);
  __shared__ float red[4];
  if ((tid & 63) == 0) red[tid >> 6] = s;
  __syncthreads();
  if (tid == 0){
    float t = red[0] + red[1] + red[2] + red[3] + b5[0];
    out[b] = lrelu(t);
  }
}

// ---------------------------------------------------------------------------
extern "C" void kernel_launch(void* const* d_in, const int* in_sizes, int n_in,
                              void* d_out, int out_size, void* d_ws, size_t ws_size,
                              hipStream_t stream)
{
  const float* x    = (const float*)d_in[0];
  const float* h0r  = (const float*)d_in[1];
  const float* h0i  = (const float*)d_in[2];
  const float* Urw  = (const float*)d_in[3];
  const float* Urb  = (const float*)d_in[4];
  const float* Uiw  = (const float*)d_in[5];
  const float* Uib  = (const float*)d_in[6];
  const float* Wrw  = (const float*)d_in[7];
  const float* Wrb  = (const float*)d_in[8];
  const float* Wiw  = (const float*)d_in[9];
  const float* Wib  = (const float*)d_in[10];
  const float* l1rw = (const float*)d_in[11];
  const float* l1rb = (const float*)d_in[12];
  const float* l1iw = (const float*)d_in[13];
  const float* l1ib = (const float*)d_in[14];
  const float* l2rw = (const float*)d_in[15];
  const float* l2rb = (const float*)d_in[16];
  const float* l2iw = (const float*)d_in[17];
  const float* l2ib = (const float*)d_in[18];
  const float* l3rw = (const float*)d_in[19];
  const float* l3rb = (const float*)d_in[20];
  const float* l3iw = (const float*)d_in[21];
  const float* l3ib = (const float*)d_in[22];
  const float* l5w  = (const float*)d_in[23];
  const float* l5b  = (const float*)d_in[24];
  (void)in_sizes; (void)n_in; (void)out_size; (void)ws_size;

  char* p = (char*)d_ws;
  auto alloc = [&](size_t bytes)->char*{ char* r = p; p += (bytes + 255) & ~(size_t)255; return r; };
  _Float16* xh  = (_Float16*)alloc(25165824ull*2);   // x as f16 [b*64+t][1536]
  _Float16* cb  = (_Float16*)alloc(25165824ull*2);   // c [t][b][1536] f16
  _Float16* Wu  = (_Float16*)alloc(2359296ull*2);    // [[Ur,-Ui],[Ui,Ur]]
  _Float16* Wc  = (_Float16*)alloc(2359296ull*2);    // [[Wr,-Wi],[Wi,Wr]]
  float*    ub  = (float*)alloc(1536*4);
  float*    cbs = (float*)alloc(1536*4);
  _Float16* B1  = (_Float16*)alloc(4718592ull*2);    // [l1r;l1i] (6144x768)
  float*    b1  = (float*)alloc(6144*4);
  _Float16* B2  = (_Float16*)alloc(18874368ull*2);   // [l2r;l2i] (6144x3072)
  float*    b2  = (float*)alloc(6144*4);
  _Float16* B3  = (_Float16*)alloc(18874368ull*2);   // [l3r;l3i]
  float*    b3  = (float*)alloc(6144*4);
  _Float16* hA  = (_Float16*)alloc(393216ull*2);     // h double-buffer [256][1536]
  _Float16* hB  = (_Float16*)alloc(393216ull*2);
  _Float16* A2  = (_Float16*)alloc(393216ull*2);     // [512][768]
  _Float16* LC  = (_Float16*)alloc(3145728ull*2);    // [512][6144]
  _Float16* yb  = (_Float16*)alloc(1572864ull*2);    // [512][3072]

  // --- prep / converts ---
  k_f2h<<<dim3(2048), dim3(256), 0, stream>>>(x, xh, 25165824L/8);
  k_build_cplx<<<dim3(1152), dim3(256), 0, stream>>>(Urw, Uiw, Urb, Uib, Wu, ub);
  k_build_cplx<<<dim3(1152), dim3(256), 0, stream>>>(Wrw, Wiw, Wrb, Wib, Wc, cbs);
  k_build_cat<<<dim3(2048), dim3(256), 0, stream>>>(l1rw, l1iw, B1, 3072, 768);
  k_cat_bias<<<dim3(24), dim3(256), 0, stream>>>(l1rb, l1ib, b1, 3072);
  k_build_cat<<<dim3(2048), dim3(256), 0, stream>>>(l2rw, l2iw, B2, 3072, 3072);
  k_cat_bias<<<dim3(24), dim3(256), 0, stream>>>(l2rb, l2ib, b2, 3072);
  k_build_cat<<<dim3(2048), dim3(256), 0, stream>>>(l3rw, l3iw, B3, 3072, 3072);
  k_cat_bias<<<dim3(24), dim3(256), 0, stream>>>(l3rb, l3ib, b3, 3072);
  k_hinit<<<dim3(192), dim3(256), 0, stream>>>(h0r, h0i, hA);

  // --- U projection: c[t][b][:] = Wu @ x[b][t][:] + ubias ---
  gemm_bt<128,128,32,2,2,0><<<dim3(1536), dim3(256), 0, stream>>>(
      xh, Wu, ub, nullptr, cb, 16384, 1536, 1536);

  // --- recurrence: 64 sequential small GEMMs (96 blocks each for CU coverage) ---
  _Float16* hc = hA; _Float16* hn = hB;
  for (int t = 0; t < 64; ++t) {
    gemm_bt<32,128,64,2,2,1><<<dim3(96), dim3(256), 0, stream>>>(
        hc, Wc, cbs, cb + (size_t)t*393216, hn, 256, 1536, 1536);
    _Float16* tmp = hc; hc = hn; hn = tmp;
  }

  // --- MLP ---
  k_pack<<<dim3(192), dim3(256), 0, stream>>>(hc, A2);
  gemm_bt<256,128,64,4,2,2><<<dim3(96), dim3(512), 0, stream>>>(
      A2, B1, b1, nullptr, LC, 512, 6144, 768);
  k_combine<<<dim3(384), dim3(256), 0, stream>>>(LC, yb);
  gemm_bt<256,128,64,4,2,2><<<dim3(96), dim3(512), 0, stream>>>(
      yb, B2, b2, nullptr, LC, 512, 6144, 3072);
  k_combine<<<dim3(384), dim3(256), 0, stream>>>(LC, yb);
  gemm_bt<256,128,64,4,2,2><<<dim3(96), dim3(512), 0, stream>>>(
      yb, B3, b3, nullptr, LC, 512, 6144, 3072);
  k_combine<<<dim3(384), dim3(256), 0, stream>>>(LC, yb);

  // --- head ---
  k_final<<<dim3(256), dim3(256), 0, stream>>>(yb, l5w, l5b, (float*)d_out);
}

// Round 7
// 1757.127 us; speedup vs baseline: 1.1929x; 1.1929x over previous
//
#include <hip/hip_runtime.h>
#include <stdint.h>

typedef _Float16 h8 __attribute__((ext_vector_type(8)));
typedef float f4 __attribute__((ext_vector_type(4)));

#define DEV __device__ __forceinline__

DEV float lrelu(float v){ return v >= 0.f ? v : 0.1f * v; }

DEV void gl_lds16(const void* g, void* l){
  __builtin_amdgcn_global_load_lds(
      (const __attribute__((address_space(1))) void*)g,
      (__attribute__((address_space(3))) void*)l, 16, 0, 0);
}

// ---------------------------------------------------------------------------
// GEMM: acc[m][n] = sum_k A[m][k] * B[n][k]   (A: [M][K] f16, B: [N][K] f16)
// MODE 0: D[((m&63)*256 + (m>>6))*N + n] = acc + bias[n]          (U-path -> c[t][b][n])
// MODE 2: D[m*N+n] = lrelu(acc + bias[n])                         (MLP layers)
// ---------------------------------------------------------------------------
template<int BM,int BN,int BK,int WR,int WC,int MODE>
__global__ __launch_bounds__(WR*WC*64)
void gemm_bt(const _Float16* __restrict__ A, const _Float16* __restrict__ Bw,
             const float* __restrict__ bias, const _Float16* __restrict__ Cterm,
             _Float16* __restrict__ D, int M, int N, int K)
{
  constexpr int NW  = WR*WC;
  constexpr int WMT = BM/WR, WNT = BN/WC;
  constexpr int MI  = WMT/16, NI = WNT/16;
  constexpr int RPI = 512/BK;                 // rows per 1KB global_load_lds issue
  constexpr int AIS = BM/RPI/NW, BIS = BN/RPI/NW;
  static_assert(AIS*RPI*NW == BM && BIS*RPI*NW == BN, "tile/stage mismatch");

  __shared__ __align__(16) _Float16 As[BM][BK];
  __shared__ __align__(16) _Float16 Bs[BN][BK];

  int wg = blockIdx.x;
  { int q = (int)gridDim.x >> 3; wg = (wg & 7) * q + (wg >> 3); }  // XCD swizzle (grids %8==0)
  const int nt = N / BN;
  const int m0 = (wg / nt) * BM, n0 = (wg % nt) * BN;

  const int tid = threadIdx.x, w = tid >> 6, lane = tid & 63;
  const int wm = (w / WC) * WMT, wn = (w % WC) * WNT;
  const int lrow = lane / (BK/8), lkb = (lane % (BK/8)) * 8;
  const int fr = lane & 15, fk = (lane >> 4) * 8, rrow = (lane >> 4) * 4;

  f4 acc[MI][NI];
  f4 zero = {0.f, 0.f, 0.f, 0.f};
  #pragma unroll
  for (int i = 0; i < MI; ++i)
    #pragma unroll
    for (int j = 0; j < NI; ++j) acc[i][j] = zero;

  for (int k0 = 0; k0 < K; k0 += BK) {
    __syncthreads();
    #pragma unroll
    for (int i = 0; i < AIS; ++i) {
      const int r0 = (w*AIS + i) * RPI;
      gl_lds16(A + (size_t)(m0 + r0 + lrow)*K + (k0 + lkb), (void*)&As[r0][0]);
    }
    #pragma unroll
    for (int i = 0; i < BIS; ++i) {
      const int r0 = (w*BIS + i) * RPI;
      gl_lds16(Bw + (size_t)(n0 + r0 + lrow)*K + (k0 + lkb), (void*)&Bs[r0][0]);
    }
    __syncthreads();
    #pragma unroll
    for (int kk = 0; kk < BK; kk += 32) {
      h8 af[MI], bf[NI];
      #pragma unroll
      for (int mi = 0; mi < MI; ++mi) af[mi] = *(const h8*)&As[wm + mi*16 + fr][kk + fk];
      #pragma unroll
      for (int ni = 0; ni < NI; ++ni) bf[ni] = *(const h8*)&Bs[wn + ni*16 + fr][kk + fk];
      #pragma unroll
      for (int mi = 0; mi < MI; ++mi)
        #pragma unroll
        for (int ni = 0; ni < NI; ++ni)
          acc[mi][ni] = __builtin_amdgcn_mfma_f32_16x16x32_f16(af[mi], bf[ni], acc[mi][ni], 0, 0, 0);
    }
  }

  #pragma unroll
  for (int mi = 0; mi < MI; ++mi)
    #pragma unroll
    for (int ni = 0; ni < NI; ++ni) {
      const int n = n0 + wn + ni*16 + fr;
      const float bv = bias[n];
      #pragma unroll
      for (int r = 0; r < 4; ++r) {
        const int m = m0 + wm + mi*16 + rrow + r;
        float v = acc[mi][ni][r] + bv;
        if constexpr (MODE == 0) {
          D[(size_t)((m & 63)*256 + (m >> 6)) * N + n] = (_Float16)v;
        } else {
          v = lrelu(v);
          D[(size_t)m * N + n] = (_Float16)v;
        }
      }
    }
  (void)Cterm;
}

// ---------------------------------------------------------------------------
// Persistent cooperative scan kernel.
// Grid: 256 blocks = 8 batch-groups (g = bid&7, 32 batch rows each)
//                  x 32 n-tiles   (j = bid>>3, 48 cols each).
// Block holds Wc panel [48][1536] in LDS (padded stride 1544 -> conflict-free),
// loops 64 steps: h_out[m][n] = lrelu( sum_k Wc[n][k] h_in[m][k] + bias[n] + c[t][m][n] ),
// group-local 32-block barrier between steps (monotonic agent-scope counter).
// h double-buffered in global (hA/hB); 64 steps (even) end in hA.
// ---------------------------------------------------------------------------
__global__ __launch_bounds__(384, 1)
void k_scan(const _Float16* __restrict__ Wc, const float* __restrict__ bias,
            const _Float16* __restrict__ cb, _Float16* __restrict__ hA,
            _Float16* __restrict__ hB, int* __restrict__ bar)
{
  __shared__ __align__(16) _Float16 Bs[48 * 1544];   // 148224 B

  const int bid = blockIdx.x;
  const int g = bid & 7, j = bid >> 3;
  const int n0 = j * 48, m0 = g * 32;
  const int tid = threadIdx.x, w = tid >> 6, lane = tid & 63;
  const int wr = w / 3, wc = w % 3;                  // 2x3 wave grid (16m x 16n tiles)
  const int fr = lane & 15, fk = (lane >> 4) * 8, rrow = (lane >> 4) * 4;

  // one-time Wc panel load (reg-staged so we can pad)
  for (int idx = tid; idx < 48 * 192; idx += 384) {
    const int r = idx / 192, kc = (idx - r * 192) * 8;
    *(h8*)(&Bs[r * 1544 + kc]) = *(const h8*)(Wc + (size_t)(n0 + r) * 1536 + kc);
  }

  const int   ncol  = n0 + wc * 16 + fr;
  const float bv    = bias[ncol];
  const int   bsrow = (wc * 16 + fr) * 1544 + fk;
  const int   arowi = m0 + wr * 16 + fr;             // A-fragment row
  const int   orow  = m0 + wr * 16 + rrow;           // output row base
  int* cnt = bar + g * 32;                           // 128B-separated counters

  __syncthreads();

  const _Float16* hin = hA;
  _Float16* hout = hB;

  for (int t = 0; t < 64; ++t) {
    // prefetch c-term (independent of h; latency hides under K-loop)
    const _Float16* cp = cb + ((size_t)t * 256 + orow) * 1536 + ncol;
    const float cv0 = (float)cp[0];
    const float cv1 = (float)cp[1536];
    const float cv2 = (float)cp[3072];
    const float cv3 = (float)cp[4608];

    const _Float16* arow = hin + (size_t)arowi * 1536 + fk;
    h8 a[8], b[8];
    #pragma unroll
    for (int i = 0; i < 8; ++i) {
      a[i] = *(const h8*)(arow + i * 32);
      b[i] = *(const h8*)(&Bs[bsrow + i * 32]);
    }
    f4 acc = {0.f, 0.f, 0.f, 0.f};
    #pragma unroll
    for (int c8 = 0; c8 < 48; c8 += 8) {
      #pragma unroll
      for (int i = 0; i < 8; ++i) {
        acc = __builtin_amdgcn_mfma_f32_16x16x32_f16(a[i], b[i], acc, 0, 0, 0);
        if (c8 + 8 < 48) {
          a[i] = *(const h8*)(arow + (c8 + 8 + i) * 32);
          b[i] = *(const h8*)(&Bs[bsrow + (c8 + 8 + i) * 32]);
        }
      }
    }

    _Float16* op = hout + (size_t)orow * 1536 + ncol;
    op[0]    = (_Float16)lrelu(acc[0] + bv + cv0);
    op[1536] = (_Float16)lrelu(acc[1] + bv + cv1);
    op[3072] = (_Float16)lrelu(acc[2] + bv + cv2);
    op[4608] = (_Float16)lrelu(acc[3] + bv + cv3);

    __syncthreads();   // emits s_waitcnt vmcnt(0): all block stores drained
    if (tid == 0) {
      __hip_atomic_fetch_add(cnt, 1, __ATOMIC_RELEASE, __HIP_MEMORY_SCOPE_AGENT);
      const int target = 32 * (t + 1);
      while (__hip_atomic_load(cnt, __ATOMIC_RELAXED, __HIP_MEMORY_SCOPE_AGENT) < target)
        __builtin_amdgcn_s_sleep(2);
      (void)__hip_atomic_load(cnt, __ATOMIC_ACQUIRE, __HIP_MEMORY_SCOPE_AGENT); // one inv
    }
    __syncthreads();

    _Float16* tmp = (_Float16*)hin; hin = hout; hout = tmp;
  }
}

// ---------------------------------------------------------------------------
// Prep / elementwise kernels (all vectorized 8 elems/thread, grid-stride)
// ---------------------------------------------------------------------------
__global__ void k_f2h(const float* __restrict__ s, _Float16* __restrict__ d, long n8){
  const long str = (long)gridDim.x * blockDim.x;
  for (long i = (long)blockIdx.x*blockDim.x + threadIdx.x; i < n8; i += str){
    const long e = i*8;
    f4 a = *(const f4*)(s+e), b = *(const f4*)(s+e+4);
    h8 h = {(_Float16)a[0],(_Float16)a[1],(_Float16)a[2],(_Float16)a[3],
            (_Float16)b[0],(_Float16)b[1],(_Float16)b[2],(_Float16)b[3]};
    *(h8*)(d+e) = h;
  }
}

// W = [[Ar, -Ai],[Ai, Ar]] (1536x1536 f16), bias = [br-bi ; br+bi]
__global__ void k_build_cplx(const float* __restrict__ Ar, const float* __restrict__ Ai,
                             const float* __restrict__ br, const float* __restrict__ bi,
                             _Float16* __restrict__ W, float* __restrict__ bias)
{
  const long n8 = 1536L*1536/8;
  const long str = (long)gridDim.x*blockDim.x;
  const long t0 = (long)blockIdx.x*blockDim.x + threadIdx.x;
  if (t0 < 1536) bias[t0] = (t0 < 768) ? br[t0] - bi[t0] : br[t0-768] + bi[t0-768];
  for (long i = t0; i < n8; i += str){
    const long e = i*8;
    const int n = (int)(e / 1536), k = (int)(e % 1536);
    const float* src; float sg = 1.f;
    if (n < 768) { if (k < 768) src = Ar + (long)n*768 + k; else { src = Ai + (long)n*768 + (k-768); sg = -1.f; } }
    else         { if (k < 768) src = Ai + (long)(n-768)*768 + k; else src = Ar + (long)(n-768)*768 + (k-768); }
    f4 a = *(const f4*)src, b = *(const f4*)(src+4);
    h8 h = {(_Float16)(a[0]*sg),(_Float16)(a[1]*sg),(_Float16)(a[2]*sg),(_Float16)(a[3]*sg),
            (_Float16)(b[0]*sg),(_Float16)(b[1]*sg),(_Float16)(b[2]*sg),(_Float16)(b[3]*sg)};
    *(h8*)(W + e) = h;
  }
}

// W = [lr ; li]  ((2*Nh) x K f16)
__global__ void k_build_cat(const float* __restrict__ lr, const float* __restrict__ li,
                            _Float16* __restrict__ W, int Nh, int K)
{
  const long n8 = (long)Nh*2*K/8;
  const long str = (long)gridDim.x*blockDim.x;
  for (long i = (long)blockIdx.x*blockDim.x + threadIdx.x; i < n8; i += str){
    const long e = i*8;
    const int n = (int)(e / K), k = (int)(e % K);
    const float* src = (n < Nh) ? lr + (long)n*K + k : li + (long)(n-Nh)*K + k;
    f4 a = *(const f4*)src, b = *(const f4*)(src+4);
    h8 h = {(_Float16)a[0],(_Float16)a[1],(_Float16)a[2],(_Float16)a[3],
            (_Float16)b[0],(_Float16)b[1],(_Float16)b[2],(_Float16)b[3]};
    *(h8*)(W + e) = h;
  }
}

__global__ void k_cat_bias(const float* __restrict__ brr, const float* __restrict__ bii,
                           float* __restrict__ bias, int Nh){
  const int t = blockIdx.x*blockDim.x + threadIdx.x;
  if (t < 2*Nh) bias[t] = (t < Nh) ? brr[t] : bii[t - Nh];
}

// h0 f16 [256][1536] = [h0r | h0i]
__global__ void k_hinit(const float* __restrict__ h0r, const float* __restrict__ h0i,
                        _Float16* __restrict__ h){
  const long n8 = 256L*1536/8;
  const long str = (long)gridDim.x*blockDim.x;
  for (long i = (long)blockIdx.x*blockDim.x + threadIdx.x; i < n8; i += str){
    const long e = i*8;
    const int b = (int)(e / 1536), j = (int)(e % 1536);
    const float* src = (j < 768) ? h0r + (long)b*768 + j : h0i + (long)b*768 + (j-768);
    f4 a = *(const f4*)src, c = *(const f4*)(src+4);
    h8 h2 = {(_Float16)a[0],(_Float16)a[1],(_Float16)a[2],(_Float16)a[3],
             (_Float16)c[0],(_Float16)c[1],(_Float16)c[2],(_Float16)c[3]};
    *(h8*)(h + e) = h2;
  }
}

// A2 [512][768] = [hr ; hi] from h [256][1536]
__global__ void k_pack(const _Float16* __restrict__ h, _Float16* __restrict__ A2){
  const long n8 = 512L*768/8;
  const long str = (long)gridDim.x*blockDim.x;
  for (long i = (long)blockIdx.x*blockDim.x + threadIdx.x; i < n8; i += str){
    const long e = i*8;
    const int m = (int)(e / 768), k = (int)(e % 768);
    const _Float16* src = (m < 256) ? h + (long)m*1536 + k : h + (long)(m-256)*1536 + 768 + k;
    *(h8*)(A2 + e) = *(const h8*)src;
  }
}

// y[b][j] = LC[b][j] - LC[256+b][3072+j] ; y[256+b][j] = LC[256+b][j] + LC[b][3072+j]
__global__ void k_combine(const _Float16* __restrict__ LC, _Float16* __restrict__ y){
  const long n8 = 256L*3072/8;
  const long str = (long)gridDim.x*blockDim.x;
  for (long i = (long)blockIdx.x*blockDim.x + threadIdx.x; i < n8; i += str){
    const long e = i*8;
    const int b = (int)(e / 3072), j = (int)(e % 3072);
    h8 arr = *(const h8*)(LC + (long)b*6144 + j);
    h8 aii = *(const h8*)(LC + (long)(256+b)*6144 + 3072 + j);
    h8 air = *(const h8*)(LC + (long)(256+b)*6144 + j);
    h8 ari = *(const h8*)(LC + (long)b*6144 + 3072 + j);
    h8 yr, yi;
    #pragma unroll
    for (int t = 0; t < 8; ++t){
      yr[t] = (_Float16)((float)arr[t] - (float)aii[t]);
      yi[t] = (_Float16)((float)air[t] + (float)ari[t]);
    }
    *(h8*)(y + (long)b*3072 + j) = yr;
    *(h8*)(y + (long)(256+b)*3072 + j) = yi;
  }
}

// out[b] = lrelu( dot(concat(xrn[b], xin[b]), w5) + b5 )
__global__ void k_final(const _Float16* __restrict__ y, const float* __restrict__ w5,
                        const float* __restrict__ b5, float* __restrict__ out){
  const int b = blockIdx.x, tid = threadIdx.x;
  float s = 0.f;
  for (int j = tid; j < 6144; j += 256){
    float v = (j < 3072) ? (float)y[(long)b*3072 + j] : (float)y[(long)(256+b)*3072 + (j-3072)];
    s += v * w5[j];
  }
  #pragma unroll
  for (int off = 32; off; off >>= 1) s += __shfl_down(s, off);
  __shared__ float red[4];
  if ((tid & 63) == 0) red[tid >> 6] = s;
  __syncthreads();
  if (tid == 0){
    float t = red[0] + red[1] + red[2] + red[3] + b5[0];
    out[b] = lrelu(t);
  }
}

// ---------------------------------------------------------------------------
extern "C" void kernel_launch(void* const* d_in, const int* in_sizes, int n_in,
                              void* d_out, int out_size, void* d_ws, size_t ws_size,
                              hipStream_t stream)
{
  const float* x    = (const float*)d_in[0];
  const float* h0r  = (const float*)d_in[1];
  const float* h0i  = (const float*)d_in[2];
  const float* Urw  = (const float*)d_in[3];
  const float* Urb  = (const float*)d_in[4];
  const float* Uiw  = (const float*)d_in[5];
  const float* Uib  = (const float*)d_in[6];
  const float* Wrw  = (const float*)d_in[7];
  const float* Wrb  = (const float*)d_in[8];
  const float* Wiw  = (const float*)d_in[9];
  const float* Wib  = (const float*)d_in[10];
  const float* l1rw = (const float*)d_in[11];
  const float* l1rb = (const float*)d_in[12];
  const float* l1iw = (const float*)d_in[13];
  const float* l1ib = (const float*)d_in[14];
  const float* l2rw = (const float*)d_in[15];
  const float* l2rb = (const float*)d_in[16];
  const float* l2iw = (const float*)d_in[17];
  const float* l2ib = (const float*)d_in[18];
  const float* l3rw = (const float*)d_in[19];
  const float* l3rb = (const float*)d_in[20];
  const float* l3iw = (const float*)d_in[21];
  const float* l3ib = (const float*)d_in[22];
  const float* l5w  = (const float*)d_in[23];
  const float* l5b  = (const float*)d_in[24];
  (void)in_sizes; (void)n_in; (void)out_size; (void)ws_size;

  char* p = (char*)d_ws;
  auto alloc = [&](size_t bytes)->char*{ char* r = p; p += (bytes + 255) & ~(size_t)255; return r; };
  _Float16* xh  = (_Float16*)alloc(25165824ull*2);   // x as f16 [b*64+t][1536]
  _Float16* cb  = (_Float16*)alloc(25165824ull*2);   // c [t][b][1536] f16
  _Float16* Wu  = (_Float16*)alloc(2359296ull*2);    // [[Ur,-Ui],[Ui,Ur]]
  _Float16* Wc  = (_Float16*)alloc(2359296ull*2);    // [[Wr,-Wi],[Wi,Wr]]
  float*    ub  = (float*)alloc(1536*4);
  float*    cbs = (float*)alloc(1536*4);
  _Float16* B1  = (_Float16*)alloc(4718592ull*2);    // [l1r;l1i] (6144x768)
  float*    b1  = (float*)alloc(6144*4);
  _Float16* B2  = (_Float16*)alloc(18874368ull*2);   // [l2r;l2i] (6144x3072)
  float*    b2  = (float*)alloc(6144*4);
  _Float16* B3  = (_Float16*)alloc(18874368ull*2);   // [l3r;l3i]
  float*    b3  = (float*)alloc(6144*4);
  _Float16* hA  = (_Float16*)alloc(393216ull*2);     // h double-buffer [256][1536]
  _Float16* hB  = (_Float16*)alloc(393216ull*2);
  _Float16* A2  = (_Float16*)alloc(393216ull*2);     // [512][768]
  _Float16* LC  = (_Float16*)alloc(3145728ull*2);    // [512][6144]
  _Float16* yb  = (_Float16*)alloc(1572864ull*2);    // [512][3072]
  int*      bar = (int*)alloc(8*32*4);               // group barrier counters

  // --- prep / converts ---
  k_f2h<<<dim3(2048), dim3(256), 0, stream>>>(x, xh, 25165824L/8);
  k_build_cplx<<<dim3(1152), dim3(256), 0, stream>>>(Urw, Uiw, Urb, Uib, Wu, ub);
  k_build_cplx<<<dim3(1152), dim3(256), 0, stream>>>(Wrw, Wiw, Wrb, Wib, Wc, cbs);
  k_build_cat<<<dim3(2048), dim3(256), 0, stream>>>(l1rw, l1iw, B1, 3072, 768);
  k_cat_bias<<<dim3(24), dim3(256), 0, stream>>>(l1rb, l1ib, b1, 3072);
  k_build_cat<<<dim3(2048), dim3(256), 0, stream>>>(l2rw, l2iw, B2, 3072, 3072);
  k_cat_bias<<<dim3(24), dim3(256), 0, stream>>>(l2rb, l2ib, b2, 3072);
  k_build_cat<<<dim3(2048), dim3(256), 0, stream>>>(l3rw, l3iw, B3, 3072, 3072);
  k_cat_bias<<<dim3(24), dim3(256), 0, stream>>>(l3rb, l3ib, b3, 3072);
  k_hinit<<<dim3(192), dim3(256), 0, stream>>>(h0r, h0i, hA);

  // --- U projection: c[t][b][:] = Wu @ x[b][t][:] + ubias ---
  gemm_bt<128,128,64,2,2,0><<<dim3(1536), dim3(256), 0, stream>>>(
      xh, Wu, ub, nullptr, cb, 16384, 1536, 1536);

  // --- recurrence: one persistent cooperative kernel, 64 steps ---
  hipMemsetAsync(bar, 0, 8*32*sizeof(int), stream);
  {
    void* args[] = { (void*)&Wc, (void*)&cbs, (void*)&cb,
                     (void*)&hA, (void*)&hB, (void*)&bar };
    hipLaunchCooperativeKernel(reinterpret_cast<void*>(&k_scan),
                               dim3(256), dim3(384), args, 0, stream);
  }

  // --- MLP ---
  k_pack<<<dim3(192), dim3(256), 0, stream>>>(hA, A2);
  gemm_bt<256,128,64,4,2,2><<<dim3(96), dim3(512), 0, stream>>>(
      A2, B1, b1, nullptr, LC, 512, 6144, 768);
  k_combine<<<dim3(384), dim3(256), 0, stream>>>(LC, yb);
  gemm_bt<256,128,64,4,2,2><<<dim3(96), dim3(512), 0, stream>>>(
      yb, B2, b2, nullptr, LC, 512, 6144, 3072);
  k_combine<<<dim3(384), dim3(256), 0, stream>>>(LC, yb);
  gemm_bt<256,128,64,4,2,2><<<dim3(96), dim3(512), 0, stream>>>(
      yb, B3, b3, nullptr, LC, 512, 6144, 3072);
  k_combine<<<dim3(384), dim3(256), 0, stream>>>(LC, yb);

  // --- head ---
  k_final<<<dim3(256), dim3(256), 0, stream>>>(yb, l5w, l5b, (float*)d_out);
}